// Round 12
// baseline (564.466 us; speedup 1.0000x reference)
//
#include <hip/hip_runtime.h>
#include <hip/hip_bf16.h>
#include <cstdint>
#include <cstdio>

#define NUM_T   8192
#define HDIM    1024
#define IDIM    4096
#define NEXP    8

#define ALGN    128                 // expert group alignment (= tile M)
#define RB      136                 // ceil((16384 + 8*127)/128)
#define MAXROWS (RB * 128)          // 17408 padded pair-rows
#define TPB     16                  // router tokens per block
#define GEMM_GRID 1024              // persistent blocks: 4/CU x 256 CU

typedef __attribute__((ext_vector_type(8))) short short8;
typedef __attribute__((ext_vector_type(4))) float f32x4;

__device__ __forceinline__ unsigned short f32_to_bf16(float f) {
  uint32_t u = __float_as_uint(f);
  u += 0x7fffu + ((u >> 16) & 1u);   // RNE; inputs are finite
  return (unsigned short)(u >> 16);
}
__device__ __forceinline__ float bf16_to_f32(unsigned short u) {
  return __uint_as_float(((uint32_t)u) << 16);
}
// bijective XCD swizzle: launch-order bid -> logical wgid, 8 contiguous chunks
__device__ __forceinline__ int xcd_swz(int bid, int nwg) {
  const int q = nwg >> 3, r = nwg & 7;
  const int x = bid & 7, i = bid >> 3;
  return (x < r ? x * (q + 1) : r * (q + 1) + (x - r) * q) + i;
}

// ---------------- fp32 -> bf16 convert, both weight tensors in one launch ----------------
__global__ void cvt2_kernel(const float* __restrict__ in0, unsigned short* __restrict__ out0,
                            int n4_0,
                            const float* __restrict__ in1, unsigned short* __restrict__ out1,
                            int n4_total) {
  int i = blockIdx.x * blockDim.x + threadIdx.x;
  const int stride = gridDim.x * blockDim.x;
  for (; i < n4_total; i += stride) {
    const float* in  = (i < n4_0) ? in0  : in1;
    unsigned short* out = (i < n4_0) ? out0 : out1;
    const int j = (i < n4_0) ? i : i - n4_0;
    const float4 v = ((const float4*)in)[j];
    ushort4 o;
    o.x = f32_to_bf16(v.x); o.y = f32_to_bf16(v.y);
    o.z = f32_to_bf16(v.z); o.w = f32_to_bf16(v.w);
    ((ushort4*)out)[j] = o;
  }
}

// ---------------- router: float4 loads, 4 tokens/wave, block-reduced counts ----------------
__global__ void router_kernel(const float* __restrict__ x, const float* __restrict__ wg,
                              float* __restrict__ logits, int* __restrict__ tki,
                              float* __restrict__ tkg, int* __restrict__ counts,
                              unsigned short* __restrict__ xb) {
  __shared__ int s_cnt[NEXP];
  const int tid = threadIdx.x;
  if (tid < NEXP) s_cnt[tid] = 0;
  __syncthreads();

  const int wave = tid >> 6;
  const int lane = tid & 63;

#pragma unroll 1
  for (int k = 0; k < 4; ++k) {
    const int t = blockIdx.x * TPB + wave * 4 + k;
    const float* xr = x + (size_t)t * HDIM;
    unsigned short* xbr = xb + (size_t)t * HDIM;

    float acc[NEXP];
#pragma unroll
    for (int e = 0; e < NEXP; ++e) acc[e] = 0.f;

#pragma unroll
    for (int it = 0; it < 4; ++it) {
      const int off = it * 256 + lane * 4;
      const float4 xv = *(const float4*)(xr + off);
      ushort4 o;
      o.x = f32_to_bf16(xv.x); o.y = f32_to_bf16(xv.y);
      o.z = f32_to_bf16(xv.z); o.w = f32_to_bf16(xv.w);
      *(ushort4*)(xbr + off) = o;
#pragma unroll
      for (int e = 0; e < NEXP; ++e) {
        const float4 wv = *(const float4*)(wg + e * HDIM + off);
        acc[e] += xv.x * wv.x + xv.y * wv.y + xv.z * wv.z + xv.w * wv.w;
      }
    }
#pragma unroll
    for (int e = 0; e < NEXP; ++e) {
#pragma unroll
      for (int s = 32; s > 0; s >>= 1) acc[e] += __shfl_xor(acc[e], s, 64);
    }
    if (lane == 0) {
      float v0 = -1e30f, v1 = -1e30f; int i0 = 0, i1 = 0;
#pragma unroll
      for (int e = 0; e < NEXP; ++e) {
        const float v = acc[e];
        logits[(size_t)t * NEXP + e] = v;
        if (v > v0)      { v1 = v0; i1 = i0; v0 = v; i0 = e; }
        else if (v > v1) { v1 = v; i1 = e; }
      }
      const float g0 = 1.f / (1.f + expf(v1 - v0));  // softmax over top-2
      tki[t * 2] = i0; tki[t * 2 + 1] = i1;
      tkg[t * 2] = g0; tkg[t * 2 + 1] = 1.f - g0;
      atomicAdd(&s_cnt[i0], 1);
      atomicAdd(&s_cnt[i1], 1);
    }
  }
  __syncthreads();
  if (tid < NEXP) atomicAdd(&counts[tid], s_cnt[tid]);
}

// ---------------- scatter: local prefix-sum of counts (identical in every block);
// block 0 publishes off[] for the GEMMs ----------------
__global__ void scatter_kernel(const int* __restrict__ tki, const float* __restrict__ tkg,
                               const int* __restrict__ counts, int* __restrict__ off_out,
                               int* __restrict__ fill,
                               int* __restrict__ ptok, float* __restrict__ pgate,
                               int* __restrict__ inv) {
  int o[NEXP + 1];
  o[0] = 0;
#pragma unroll
  for (int e = 0; e < NEXP; ++e) o[e + 1] = o[e] + ((counts[e] + ALGN - 1) & ~(ALGN - 1));
  if (blockIdx.x == 0 && threadIdx.x == 0) {
#pragma unroll
    for (int e = 0; e <= NEXP; ++e) off_out[e] = o[e];
  }
  const int t = blockIdx.x * 256 + threadIdx.x;
  if (t >= NUM_T) return;
#pragma unroll
  for (int k = 0; k < 2; ++k) {
    const int e = tki[t * 2 + k];
    const int pos = o[e] + atomicAdd(&fill[e], 1);
    ptok[pos] = t;
    pgate[pos] = tkg[t * 2 + k];
    inv[t * 2 + k] = pos;
  }
}

// =====================================================================
// fc GEMM: act = gelu(X[perm] @ Wfc[e]^T)
// m97-regime: 128x128 tile, 4 waves, BK=64, single-buffer 32 KB LDS,
// 2 barriers/K-step, plain C++ LDS reads, global_load_lds w16,
// XOR chunk swizzle, XCD chunk swizzle + 4x4 super-tile remap.
// PERSISTENT: grid=1024, each block loops tiles bid, bid+1024, ...
// (+1024 === 0 mod 8 keeps a block's tiles in one XCD chunk; concurrent
// window = 8 super-tiles/chunk, same L2 locality as non-persistent).
// =====================================================================
__launch_bounds__(256, 4)
__global__ void fc_gemm(const unsigned short* __restrict__ xb,
                        const unsigned short* __restrict__ wfcb,
                        const int* __restrict__ ptok,
                        const int* __restrict__ off,
                        unsigned short* __restrict__ act) {
  const int nwg = (IDIM / 128) * RB;           // 32 * 136 = 4352
  const int tid = threadIdx.x;
  const int lane = tid & 63;
  const int wid = tid >> 6;
  const int wr = wid >> 1;
  const int wc = wid & 1;

  __shared__ __align__(16) unsigned short Al[128 * 64];
  __shared__ __align__(16) unsigned short Bl[128 * 64];
  __shared__ int s_tok[128];

  int aaddr[4], baddr[4];  // byte offsets (kk=0); kk=1 is ^64
#pragma unroll
  for (int m = 0; m < 4; ++m) {
    const int row = wr * 64 + m * 16 + (lane & 15);
    aaddr[m] = row * 128 + (((lane >> 4) ^ (row & 7)) * 16);
  }
#pragma unroll
  for (int n = 0; n < 4; ++n) {
    const int row = wc * 64 + n * 16 + (lane & 15);
    baddr[n] = row * 128 + (((lane >> 4) ^ (row & 7)) * 16);
  }

#pragma unroll 1
  for (int widx = blockIdx.x; widx < nwg; widx += GEMM_GRID) {
    const int wgid = xcd_swz(widx, nwg);
    // 4x4 super-tile remap: 16 wgids per ST; 8 col-groups x 34 row-groups
    const int st = wgid >> 4, w16 = wgid & 15;
    const int row0 = ((st >> 3) * 4 + (w16 >> 2)) * 128;
    const int icol0 = ((st & 7) * 4 + (w16 & 3)) * 128;
    if (row0 >= off[8]) continue;
    int e = 0;
    while (row0 >= off[e + 1]) ++e;

    if (tid < 128) s_tok[tid] = ptok[row0 + tid];
    __syncthreads();

    const unsigned short* gA[4];
    const unsigned short* gB[4];
#pragma unroll
    for (int p = 0; p < 4; ++p) {
      const int id = p * 256 + tid;
      const int r = id >> 3;
      const int cs = (id & 7) ^ (r & 7);
      gA[p] = xb + (size_t)s_tok[r] * HDIM + cs * 8;
      gB[p] = wfcb + ((size_t)e * IDIM + icol0 + r) * HDIM + cs * 8;
    }

    f32x4 acc[4][4];
#pragma unroll
    for (int m = 0; m < 4; ++m)
#pragma unroll
      for (int n = 0; n < 4; ++n) acc[m][n] = (f32x4){0.f, 0.f, 0.f, 0.f};

    const int NS = HDIM / 64;
    for (int s = 0; s < NS; ++s) {
      const int k0 = s * 64;
      __syncthreads();               // prev step's reads done
#pragma unroll
      for (int p = 0; p < 4; ++p) {
        __builtin_amdgcn_global_load_lds(
            (const __attribute__((address_space(1))) void*)(gA[p] + k0),
            (__attribute__((address_space(3))) void*)((char*)Al + (p * 256 + tid) * 16), 16, 0, 0);
        __builtin_amdgcn_global_load_lds(
            (const __attribute__((address_space(1))) void*)(gB[p] + k0),
            (__attribute__((address_space(3))) void*)((char*)Bl + (p * 256 + tid) * 16), 16, 0, 0);
      }
      __syncthreads();               // stage landed (compiler drains vmcnt)
#pragma unroll
      for (int kk = 0; kk < 2; ++kk) {
        short8 a[4], b[4];
#pragma unroll
        for (int m = 0; m < 4; ++m) a[m] = *(const short8*)((const char*)Al + (aaddr[m] ^ (kk * 64)));
#pragma unroll
        for (int n = 0; n < 4; ++n) b[n] = *(const short8*)((const char*)Bl + (baddr[n] ^ (kk * 64)));
#pragma unroll
        for (int m = 0; m < 4; ++m)
#pragma unroll
          for (int n = 0; n < 4; ++n)
            acc[m][n] = __builtin_amdgcn_mfma_f32_16x16x32_bf16(a[m], b[n], acc[m][n], 0, 0, 0);
      }
    }

    // epilogue: exact gelu, bf16 store.  D: row=(lane>>4)*4+r, col=lane&15
#pragma unroll
    for (int m = 0; m < 4; ++m) {
      const int prow = row0 + wr * 64 + m * 16 + (lane >> 4) * 4;
#pragma unroll
      for (int n = 0; n < 4; ++n) {
        const int col = icol0 + wc * 64 + n * 16 + (lane & 15);
#pragma unroll
        for (int r = 0; r < 4; ++r) {
          const float v = acc[m][n][r];
          const float g = 0.5f * v * (1.0f + erff(v * 0.70710678118654752f));
          act[(size_t)(prow + r) * IDIM + col] = f32_to_bf16(g);
        }
      }
    }
    __syncthreads();                 // epilogue done before next tile's s_tok write
  }
}

// =====================================================================
// proj GEMM: pair[row] = gate * (act[row] @ Wproj[e]^T)
// Same persistent m97-regime structure; bf16 pair stores (no atomics).
// Persistence smooths the 1088-tiles / 1024-slots quantization.
// =====================================================================
__launch_bounds__(256, 4)
__global__ void proj_gemm(const unsigned short* __restrict__ actb,
                          const unsigned short* __restrict__ wpb,
                          const float* __restrict__ pgate,
                          const int* __restrict__ off,
                          unsigned short* __restrict__ pair) {
  const int nwg = (HDIM / 128) * RB;           // 8 * 136 = 1088
  const int tid = threadIdx.x;
  const int lane = tid & 63;
  const int wid = tid >> 6;
  const int wr = wid >> 1;
  const int wc = wid & 1;

  __shared__ __align__(16) unsigned short Al[128 * 64];
  __shared__ __align__(16) unsigned short Bl[128 * 64];
  __shared__ float s_g[128];

  int aaddr[4], baddr[4];
#pragma unroll
  for (int m = 0; m < 4; ++m) {
    const int row = wr * 64 + m * 16 + (lane & 15);
    aaddr[m] = row * 128 + (((lane >> 4) ^ (row & 7)) * 16);
  }
#pragma unroll
  for (int n = 0; n < 4; ++n) {
    const int row = wc * 64 + n * 16 + (lane & 15);
    baddr[n] = row * 128 + (((lane >> 4) ^ (row & 7)) * 16);
  }

#pragma unroll 1
  for (int widx = blockIdx.x; widx < nwg; widx += GEMM_GRID) {
    const int wgid = xcd_swz(widx, nwg);
    const int st = wgid >> 4, w16 = wgid & 15;
    const int row0 = ((st >> 1) * 4 + (w16 >> 2)) * 128;
    const int hcol0 = ((st & 1) * 4 + (w16 & 3)) * 128;
    if (row0 >= off[8]) continue;
    int e = 0;
    while (row0 >= off[e + 1]) ++e;

    if (tid < 128) s_g[tid] = pgate[row0 + tid];
    __syncthreads();

    const unsigned short* gA[4];
    const unsigned short* gB[4];
#pragma unroll
    for (int p = 0; p < 4; ++p) {
      const int id = p * 256 + tid;
      const int r = id >> 3;
      const int cs = (id & 7) ^ (r & 7);
      gA[p] = actb + (size_t)(row0 + r) * IDIM + cs * 8;
      gB[p] = wpb + ((size_t)e * HDIM + hcol0 + r) * IDIM + cs * 8;
    }

    f32x4 acc[4][4];
#pragma unroll
    for (int m = 0; m < 4; ++m)
#pragma unroll
      for (int n = 0; n < 4; ++n) acc[m][n] = (f32x4){0.f, 0.f, 0.f, 0.f};

    const int NS = IDIM / 64;
    for (int s = 0; s < NS; ++s) {
      const int k0 = s * 64;
      __syncthreads();
#pragma unroll
      for (int p = 0; p < 4; ++p) {
        __builtin_amdgcn_global_load_lds(
            (const __attribute__((address_space(1))) void*)(gA[p] + k0),
            (__attribute__((address_space(3))) void*)((char*)Al + (p * 256 + tid) * 16), 16, 0, 0);
        __builtin_amdgcn_global_load_lds(
            (const __attribute__((address_space(1))) void*)(gB[p] + k0),
            (__attribute__((address_space(3))) void*)((char*)Bl + (p * 256 + tid) * 16), 16, 0, 0);
      }
      __syncthreads();
#pragma unroll
      for (int kk = 0; kk < 2; ++kk) {
        short8 a[4], b[4];
#pragma unroll
        for (int m = 0; m < 4; ++m) a[m] = *(const short8*)((const char*)Al + (aaddr[m] ^ (kk * 64)));
#pragma unroll
        for (int n = 0; n < 4; ++n) b[n] = *(const short8*)((const char*)Bl + (baddr[n] ^ (kk * 64)));
#pragma unroll
        for (int m = 0; m < 4; ++m)
#pragma unroll
          for (int n = 0; n < 4; ++n)
            acc[m][n] = __builtin_amdgcn_mfma_f32_16x16x32_bf16(a[m], b[n], acc[m][n], 0, 0, 0);
      }
    }

    // epilogue: scale by gate, bf16 store into pair rows (pads have gate 0)
#pragma unroll
    for (int m = 0; m < 4; ++m) {
      const int lr = wr * 64 + m * 16 + (lane >> 4) * 4;
#pragma unroll
      for (int n = 0; n < 4; ++n) {
        const int col = hcol0 + wc * 64 + n * 16 + (lane & 15);
#pragma unroll
        for (int r = 0; r < 4; ++r) {
          const float g = s_g[lr + r];
          pair[(size_t)(row0 + lr + r) * HDIM + col] = f32_to_bf16(g * acc[m][n][r]);
        }
      }
    }
    __syncthreads();                 // epilogue done before next tile's s_g write
  }
}

// ---------------- combine: out[t] = pair[inv[t,0]] + pair[inv[t,1]] ----------------
__global__ void combine_kernel(const unsigned short* __restrict__ pair,
                               const int* __restrict__ inv, float* __restrict__ out) {
  const int gid = blockIdx.x * 256 + threadIdx.x;     // NUM_T*HDIM/8 threads
  const int t = gid >> 7;
  const int c8 = (gid & 127) << 3;
  const short8 v0 = *(const short8*)(pair + (size_t)inv[t * 2] * HDIM + c8);
  const short8 v1 = *(const short8*)(pair + (size_t)inv[t * 2 + 1] * HDIM + c8);
  float o[8];
#pragma unroll
  for (int j = 0; j < 8; ++j)
    o[j] = bf16_to_f32((unsigned short)v0[j]) + bf16_to_f32((unsigned short)v1[j]);
  float* dst = out + (size_t)t * HDIM + c8;
  ((float4*)dst)[0] = (float4){o[0], o[1], o[2], o[3]};
  ((float4*)dst)[1] = (float4){o[4], o[5], o[6], o[7]};
}

extern "C" void kernel_launch(void* const* d_in, const int* in_sizes, int n_in,
                              void* d_out, int out_size, void* d_ws, size_t ws_size,
                              hipStream_t stream) {
  const float* x   = (const float*)d_in[0];
  const float* wg  = (const float*)d_in[1];
  const float* wfc = (const float*)d_in[2];
  const float* wpj = (const float*)d_in[3];
  float* out    = (float*)d_out;
  float* logits = out + (size_t)NUM_T * HDIM;

  char* p = (char*)d_ws;
  auto alloc = [&](size_t bytes) { char* q = p; p += (bytes + 255) & ~size_t(255); return q; };
  unsigned short* xb    = (unsigned short*)alloc((size_t)NUM_T * HDIM * 2);
  unsigned short* wfcb  = (unsigned short*)alloc((size_t)NEXP * IDIM * HDIM * 2);
  unsigned short* wpb   = (unsigned short*)alloc((size_t)NEXP * HDIM * IDIM * 2);
  unsigned short* act   = (unsigned short*)alloc((size_t)MAXROWS * IDIM * 2);
  unsigned short* pair  = (unsigned short*)alloc((size_t)MAXROWS * HDIM * 2);
  int*            ptok  = (int*)alloc((size_t)MAXROWS * 4);
  float*          pgate = (float*)alloc((size_t)MAXROWS * 4);
  int*            tki   = (int*)alloc((size_t)NUM_T * 2 * 4);
  float*          tkg   = (float*)alloc((size_t)NUM_T * 2 * 4);
  int*            inv   = (int*)alloc((size_t)NUM_T * 2 * 4);
  int*            counts= (int*)alloc(64);
  int*            fill  = (int*)alloc(64);
  int*            off   = (int*)alloc(64);
  const size_t need = (size_t)(p - (char*)d_ws);
  if (need > ws_size) {
    fprintf(stderr, "kernel_launch: ws too small: need %zu have %zu\n", need, ws_size);
    hipMemsetAsync(d_out, 0, (size_t)out_size * 4, stream);
    return;
  }

  // zero aux region (pads -> token 0 / gate 0; counts/fill for atomics)
  hipMemsetAsync(ptok, 0, (size_t)(p - (char*)ptok), stream);

  const int n4w = NEXP * IDIM * HDIM / 4;
  cvt2_kernel<<<4096, 256, 0, stream>>>(wfc, wfcb, n4w, wpj, wpb, 2 * n4w);

  router_kernel<<<NUM_T / TPB, 256, 0, stream>>>(x, wg, logits, tki, tkg, counts, xb);
  scatter_kernel<<<NUM_T / 256, 256, 0, stream>>>(tki, tkg, counts, off, fill, ptok, pgate, inv);

  fc_gemm<<<GEMM_GRID, 256, 0, stream>>>(xb, wfcb, ptok, off, act);
  proj_gemm<<<GEMM_GRID, 256, 0, stream>>>(act, wpb, pgate, off, pair);
  combine_kernel<<<NUM_T * HDIM / 8 / 256, 256, 0, stream>>>(pair, inv, out);
}

// Round 13
// 529.483 us; speedup vs baseline: 1.0661x; 1.0661x over previous
//
#include <hip/hip_runtime.h>
#include <hip/hip_bf16.h>
#include <cstdint>
#include <cstdio>

#define NUM_T   8192
#define HDIM    1024
#define IDIM    4096
#define NEXP    8

#define ALGN    128                 // expert group alignment (= tile M)
#define RB      136                 // ceil((16384 + 8*127)/128)
#define MAXROWS (RB * 128)          // 17408 padded pair-rows
#define TPB     16                  // router tokens per block
#define RT_BLOCKS (NUM_T / TPB)     // 512 router blocks inside prep_kernel
#define PREP_GRID (RT_BLOCKS + 3584)

typedef __attribute__((ext_vector_type(8))) short short8;
typedef __attribute__((ext_vector_type(4))) float f32x4;

__device__ __forceinline__ unsigned short f32_to_bf16(float f) {
  uint32_t u = __float_as_uint(f);
  u += 0x7fffu + ((u >> 16) & 1u);   // RNE; inputs are finite
  return (unsigned short)(u >> 16);
}
__device__ __forceinline__ float bf16_to_f32(unsigned short u) {
  return __uint_as_float(((uint32_t)u) << 16);
}
// bijective XCD swizzle: launch-order bid -> logical wgid, 8 contiguous chunks
__device__ __forceinline__ int xcd_swz(int bid, int nwg) {
  const int q = nwg >> 3, r = nwg & 7;
  const int x = bid & 7, i = bid >> 3;
  return (x < r ? x * (q + 1) : r * (q + 1) + (x - r) * q) + i;
}

// =====================================================================
// prep_kernel: role-split fusion of (router | weight fp32->bf16 cvt).
// Blocks [0, RT_BLOCKS): router — logits fp32, top-2 softmax, counts,
//   fused x->bf16 (latency-bound, ~20 us of work).
// Blocks [RT_BLOCKS, PREP_GRID): grid-stride cvt of wfc+wpj (BW-bound,
//   ~61 us) — the router hides entirely under it; one launch instead of two.
// =====================================================================
__global__ void prep_kernel(const float* __restrict__ x, const float* __restrict__ wg,
                            float* __restrict__ logits, int* __restrict__ tki,
                            float* __restrict__ tkg, int* __restrict__ counts,
                            unsigned short* __restrict__ xb,
                            const float* __restrict__ wfc, unsigned short* __restrict__ wfcb,
                            int n4_0,
                            const float* __restrict__ wpj, unsigned short* __restrict__ wpb,
                            int n4_total) {
  const int tid = threadIdx.x;
  if (blockIdx.x >= RT_BLOCKS) {
    // ---- cvt role ----
    const int nblk = PREP_GRID - RT_BLOCKS;
    int i = (blockIdx.x - RT_BLOCKS) * 256 + tid;
    const int stride = nblk * 256;
    for (; i < n4_total; i += stride) {
      const float* in = (i < n4_0) ? wfc : wpj;
      unsigned short* out = (i < n4_0) ? wfcb : wpb;
      const int j = (i < n4_0) ? i : i - n4_0;
      const float4 v = ((const float4*)in)[j];
      ushort4 o;
      o.x = f32_to_bf16(v.x); o.y = f32_to_bf16(v.y);
      o.z = f32_to_bf16(v.z); o.w = f32_to_bf16(v.w);
      ((ushort4*)out)[j] = o;
    }
    return;
  }
  // ---- router role ----
  __shared__ int s_cnt[NEXP];
  if (tid < NEXP) s_cnt[tid] = 0;
  __syncthreads();

  const int wave = tid >> 6;
  const int lane = tid & 63;

#pragma unroll 1
  for (int k = 0; k < 4; ++k) {
    const int t = blockIdx.x * TPB + wave * 4 + k;
    const float* xr = x + (size_t)t * HDIM;
    unsigned short* xbr = xb + (size_t)t * HDIM;

    float acc[NEXP];
#pragma unroll
    for (int e = 0; e < NEXP; ++e) acc[e] = 0.f;

#pragma unroll
    for (int it = 0; it < 4; ++it) {
      const int off = it * 256 + lane * 4;
      const float4 xv = *(const float4*)(xr + off);
      ushort4 o;
      o.x = f32_to_bf16(xv.x); o.y = f32_to_bf16(xv.y);
      o.z = f32_to_bf16(xv.z); o.w = f32_to_bf16(xv.w);
      *(ushort4*)(xbr + off) = o;
#pragma unroll
      for (int e = 0; e < NEXP; ++e) {
        const float4 wv = *(const float4*)(wg + e * HDIM + off);
        acc[e] += xv.x * wv.x + xv.y * wv.y + xv.z * wv.z + xv.w * wv.w;
      }
    }
#pragma unroll
    for (int e = 0; e < NEXP; ++e) {
#pragma unroll
      for (int s = 32; s > 0; s >>= 1) acc[e] += __shfl_xor(acc[e], s, 64);
    }
    if (lane == 0) {
      float v0 = -1e30f, v1 = -1e30f; int i0 = 0, i1 = 0;
#pragma unroll
      for (int e = 0; e < NEXP; ++e) {
        const float v = acc[e];
        logits[(size_t)t * NEXP + e] = v;
        if (v > v0)      { v1 = v0; i1 = i0; v0 = v; i0 = e; }
        else if (v > v1) { v1 = v; i1 = e; }
      }
      const float g0 = 1.f / (1.f + expf(v1 - v0));  // softmax over top-2
      tki[t * 2] = i0; tki[t * 2 + 1] = i1;
      tkg[t * 2] = g0; tkg[t * 2 + 1] = 1.f - g0;
      atomicAdd(&s_cnt[i0], 1);
      atomicAdd(&s_cnt[i1], 1);
    }
  }
  __syncthreads();
  if (tid < NEXP) atomicAdd(&counts[tid], s_cnt[tid]);
}

// ---------------- scatter: local prefix-sum of counts (identical in every block);
// block 0 publishes off[] for the GEMMs ----------------
__global__ void scatter_kernel(const int* __restrict__ tki, const float* __restrict__ tkg,
                               const int* __restrict__ counts, int* __restrict__ off_out,
                               int* __restrict__ fill,
                               int* __restrict__ ptok, float* __restrict__ pgate,
                               int* __restrict__ inv) {
  int o[NEXP + 1];
  o[0] = 0;
#pragma unroll
  for (int e = 0; e < NEXP; ++e) o[e + 1] = o[e] + ((counts[e] + ALGN - 1) & ~(ALGN - 1));
  if (blockIdx.x == 0 && threadIdx.x == 0) {
#pragma unroll
    for (int e = 0; e <= NEXP; ++e) off_out[e] = o[e];
  }
  const int t = blockIdx.x * 256 + threadIdx.x;
  if (t >= NUM_T) return;
#pragma unroll
  for (int k = 0; k < 2; ++k) {
    const int e = tki[t * 2 + k];
    const int pos = o[e] + atomicAdd(&fill[e], 1);
    ptok[pos] = t;
    pgate[pos] = tkg[t * 2 + k];
    inv[t * 2 + k] = pos;
  }
}

// =====================================================================
// fc GEMM: act = gelu(X[perm] @ Wfc[e]^T)   [R11 config — best measured]
// m97-regime: 128x128 tile, 4 waves, BK=64, single-buffer 32 KB LDS,
// 2 barriers/K-step, plain C++ LDS reads, global_load_lds w16,
// XOR chunk swizzle, XCD chunk swizzle + 4x4 super-tile remap (L2 reuse).
// (256,4): 4 blocks/CU. Non-persistent (persistence regressed, R12).
// =====================================================================
__launch_bounds__(256, 4)
__global__ void fc_gemm(const unsigned short* __restrict__ xb,
                        const unsigned short* __restrict__ wfcb,
                        const int* __restrict__ ptok,
                        const int* __restrict__ off,
                        unsigned short* __restrict__ act) {
  const int nwg = (IDIM / 128) * RB;           // 32 * 136 = 4352
  const int wgid = xcd_swz(blockIdx.x, nwg);
  const int st = wgid >> 4, w16 = wgid & 15;
  const int row0 = ((st >> 3) * 4 + (w16 >> 2)) * 128;
  const int icol0 = ((st & 7) * 4 + (w16 & 3)) * 128;
  if (row0 >= off[8]) return;
  int e = 0;
  while (row0 >= off[e + 1]) ++e;

  __shared__ __align__(16) unsigned short Al[128 * 64];
  __shared__ __align__(16) unsigned short Bl[128 * 64];
  __shared__ int s_tok[128];

  const int tid = threadIdx.x;
  if (tid < 128) s_tok[tid] = ptok[row0 + tid];
  __syncthreads();

  const unsigned short* gA[4];
  const unsigned short* gB[4];
#pragma unroll
  for (int p = 0; p < 4; ++p) {
    const int id = p * 256 + tid;
    const int r = id >> 3;
    const int cs = (id & 7) ^ (r & 7);
    gA[p] = xb + (size_t)s_tok[r] * HDIM + cs * 8;
    gB[p] = wfcb + ((size_t)e * IDIM + icol0 + r) * HDIM + cs * 8;
  }

  const int lane = tid & 63;
  const int wid = tid >> 6;
  const int wr = wid >> 1;
  const int wc = wid & 1;

  int aaddr[4], baddr[4];  // byte offsets (kk=0); kk=1 is ^64
#pragma unroll
  for (int m = 0; m < 4; ++m) {
    const int row = wr * 64 + m * 16 + (lane & 15);
    aaddr[m] = row * 128 + (((lane >> 4) ^ (row & 7)) * 16);
  }
#pragma unroll
  for (int n = 0; n < 4; ++n) {
    const int row = wc * 64 + n * 16 + (lane & 15);
    baddr[n] = row * 128 + (((lane >> 4) ^ (row & 7)) * 16);
  }

  f32x4 acc[4][4];
#pragma unroll
  for (int m = 0; m < 4; ++m)
#pragma unroll
    for (int n = 0; n < 4; ++n) acc[m][n] = (f32x4){0.f, 0.f, 0.f, 0.f};

  const int NS = HDIM / 64;
  for (int s = 0; s < NS; ++s) {
    const int k0 = s * 64;
    __syncthreads();               // prev step's reads done
#pragma unroll
    for (int p = 0; p < 4; ++p) {
      __builtin_amdgcn_global_load_lds(
          (const __attribute__((address_space(1))) void*)(gA[p] + k0),
          (__attribute__((address_space(3))) void*)((char*)Al + (p * 256 + tid) * 16), 16, 0, 0);
      __builtin_amdgcn_global_load_lds(
          (const __attribute__((address_space(1))) void*)(gB[p] + k0),
          (__attribute__((address_space(3))) void*)((char*)Bl + (p * 256 + tid) * 16), 16, 0, 0);
    }
    __syncthreads();               // stage landed (compiler drains vmcnt)
#pragma unroll
    for (int kk = 0; kk < 2; ++kk) {
      short8 a[4], b[4];
#pragma unroll
      for (int m = 0; m < 4; ++m) a[m] = *(const short8*)((const char*)Al + (aaddr[m] ^ (kk * 64)));
#pragma unroll
      for (int n = 0; n < 4; ++n) b[n] = *(const short8*)((const char*)Bl + (baddr[n] ^ (kk * 64)));
#pragma unroll
      for (int m = 0; m < 4; ++m)
#pragma unroll
        for (int n = 0; n < 4; ++n)
          acc[m][n] = __builtin_amdgcn_mfma_f32_16x16x32_bf16(a[m], b[n], acc[m][n], 0, 0, 0);
    }
  }

  // epilogue: exact gelu, bf16 store.  D: row=(lane>>4)*4+r, col=lane&15
#pragma unroll
  for (int m = 0; m < 4; ++m) {
    const int prow = row0 + wr * 64 + m * 16 + (lane >> 4) * 4;
#pragma unroll
    for (int n = 0; n < 4; ++n) {
      const int col = icol0 + wc * 64 + n * 16 + (lane & 15);
#pragma unroll
      for (int r = 0; r < 4; ++r) {
        const float v = acc[m][n][r];
        const float g = 0.5f * v * (1.0f + erff(v * 0.70710678118654752f));
        act[(size_t)(prow + r) * IDIM + col] = f32_to_bf16(g);
      }
    }
  }
}

// =====================================================================
// proj GEMM: pair[row] = gate * (act[row] @ Wproj[e]^T)   [R11 config]
// =====================================================================
__launch_bounds__(256, 4)
__global__ void proj_gemm(const unsigned short* __restrict__ actb,
                          const unsigned short* __restrict__ wpb,
                          const float* __restrict__ pgate,
                          const int* __restrict__ off,
                          unsigned short* __restrict__ pair) {
  const int nwg = (HDIM / 128) * RB;           // 8 * 136 = 1088
  const int wgid = xcd_swz(blockIdx.x, nwg);
  const int st = wgid >> 4, w16 = wgid & 15;
  const int row0 = ((st >> 1) * 4 + (w16 >> 2)) * 128;
  const int hcol0 = ((st & 1) * 4 + (w16 & 3)) * 128;
  if (row0 >= off[8]) return;
  int e = 0;
  while (row0 >= off[e + 1]) ++e;

  __shared__ __align__(16) unsigned short Al[128 * 64];
  __shared__ __align__(16) unsigned short Bl[128 * 64];
  __shared__ float s_g[128];

  const int tid = threadIdx.x;
  if (tid < 128) s_g[tid] = pgate[row0 + tid];
  __syncthreads();

  const unsigned short* gA[4];
  const unsigned short* gB[4];
#pragma unroll
  for (int p = 0; p < 4; ++p) {
    const int id = p * 256 + tid;
    const int r = id >> 3;
    const int cs = (id & 7) ^ (r & 7);
    gA[p] = actb + (size_t)(row0 + r) * IDIM + cs * 8;
    gB[p] = wpb + ((size_t)e * HDIM + hcol0 + r) * IDIM + cs * 8;
  }

  const int lane = tid & 63;
  const int wid = tid >> 6;
  const int wr = wid >> 1;
  const int wc = wid & 1;

  int aaddr[4], baddr[4];
#pragma unroll
  for (int m = 0; m < 4; ++m) {
    const int row = wr * 64 + m * 16 + (lane & 15);
    aaddr[m] = row * 128 + (((lane >> 4) ^ (row & 7)) * 16);
  }
#pragma unroll
  for (int n = 0; n < 4; ++n) {
    const int row = wc * 64 + n * 16 + (lane & 15);
    baddr[n] = row * 128 + (((lane >> 4) ^ (row & 7)) * 16);
  }

  f32x4 acc[4][4];
#pragma unroll
  for (int m = 0; m < 4; ++m)
#pragma unroll
    for (int n = 0; n < 4; ++n) acc[m][n] = (f32x4){0.f, 0.f, 0.f, 0.f};

  const int NS = IDIM / 64;
  for (int s = 0; s < NS; ++s) {
    const int k0 = s * 64;
    __syncthreads();
#pragma unroll
    for (int p = 0; p < 4; ++p) {
      __builtin_amdgcn_global_load_lds(
          (const __attribute__((address_space(1))) void*)(gA[p] + k0),
          (__attribute__((address_space(3))) void*)((char*)Al + (p * 256 + tid) * 16), 16, 0, 0);
      __builtin_amdgcn_global_load_lds(
          (const __attribute__((address_space(1))) void*)(gB[p] + k0),
          (__attribute__((address_space(3))) void*)((char*)Bl + (p * 256 + tid) * 16), 16, 0, 0);
    }
    __syncthreads();
#pragma unroll
    for (int kk = 0; kk < 2; ++kk) {
      short8 a[4], b[4];
#pragma unroll
      for (int m = 0; m < 4; ++m) a[m] = *(const short8*)((const char*)Al + (aaddr[m] ^ (kk * 64)));
#pragma unroll
      for (int n = 0; n < 4; ++n) b[n] = *(const short8*)((const char*)Bl + (baddr[n] ^ (kk * 64)));
#pragma unroll
      for (int m = 0; m < 4; ++m)
#pragma unroll
        for (int n = 0; n < 4; ++n)
          acc[m][n] = __builtin_amdgcn_mfma_f32_16x16x32_bf16(a[m], b[n], acc[m][n], 0, 0, 0);
    }
  }

  // epilogue: scale by gate, bf16 store into pair rows (pads have gate 0)
#pragma unroll
  for (int m = 0; m < 4; ++m) {
    const int lr = wr * 64 + m * 16 + (lane >> 4) * 4;
#pragma unroll
    for (int n = 0; n < 4; ++n) {
      const int col = hcol0 + wc * 64 + n * 16 + (lane & 15);
#pragma unroll
      for (int r = 0; r < 4; ++r) {
        const float g = s_g[lr + r];
        pair[(size_t)(row0 + lr + r) * HDIM + col] = f32_to_bf16(g * acc[m][n][r]);
      }
    }
  }
}

// ---------------- combine: out[t] = pair[inv[t,0]] + pair[inv[t,1]] ----------------
__global__ void combine_kernel(const unsigned short* __restrict__ pair,
                               const int* __restrict__ inv, float* __restrict__ out) {
  const int gid = blockIdx.x * 256 + threadIdx.x;     // NUM_T*HDIM/8 threads
  const int t = gid >> 7;
  const int c8 = (gid & 127) << 3;
  const short8 v0 = *(const short8*)(pair + (size_t)inv[t * 2] * HDIM + c8);
  const short8 v1 = *(const short8*)(pair + (size_t)inv[t * 2 + 1] * HDIM + c8);
  float o[8];
#pragma unroll
  for (int j = 0; j < 8; ++j)
    o[j] = bf16_to_f32((unsigned short)v0[j]) + bf16_to_f32((unsigned short)v1[j]);
  float* dst = out + (size_t)t * HDIM + c8;
  ((float4*)dst)[0] = (float4){o[0], o[1], o[2], o[3]};
  ((float4*)dst)[1] = (float4){o[4], o[5], o[6], o[7]};
}

extern "C" void kernel_launch(void* const* d_in, const int* in_sizes, int n_in,
                              void* d_out, int out_size, void* d_ws, size_t ws_size,
                              hipStream_t stream) {
  const float* x   = (const float*)d_in[0];
  const float* wg  = (const float*)d_in[1];
  const float* wfc = (const float*)d_in[2];
  const float* wpj = (const float*)d_in[3];
  float* out    = (float*)d_out;
  float* logits = out + (size_t)NUM_T * HDIM;

  char* p = (char*)d_ws;
  auto alloc = [&](size_t bytes) { char* q = p; p += (bytes + 255) & ~size_t(255); return q; };
  unsigned short* xb    = (unsigned short*)alloc((size_t)NUM_T * HDIM * 2);
  unsigned short* wfcb  = (unsigned short*)alloc((size_t)NEXP * IDIM * HDIM * 2);
  unsigned short* wpb   = (unsigned short*)alloc((size_t)NEXP * HDIM * IDIM * 2);
  unsigned short* act   = (unsigned short*)alloc((size_t)MAXROWS * IDIM * 2);
  unsigned short* pair  = (unsigned short*)alloc((size_t)MAXROWS * HDIM * 2);
  int*            ptok  = (int*)alloc((size_t)MAXROWS * 4);
  float*          pgate = (float*)alloc((size_t)MAXROWS * 4);
  int*            tki   = (int*)alloc((size_t)NUM_T * 2 * 4);
  float*          tkg   = (float*)alloc((size_t)NUM_T * 2 * 4);
  int*            inv   = (int*)alloc((size_t)NUM_T * 2 * 4);
  int*            counts= (int*)alloc(64);
  int*            fill  = (int*)alloc(64);
  int*            off   = (int*)alloc(64);
  const size_t need = (size_t)(p - (char*)d_ws);
  if (need > ws_size) {
    fprintf(stderr, "kernel_launch: ws too small: need %zu have %zu\n", need, ws_size);
    hipMemsetAsync(d_out, 0, (size_t)out_size * 4, stream);
    return;
  }

  // zero aux region (pads -> token 0 / gate 0; counts/fill for atomics)
  hipMemsetAsync(ptok, 0, (size_t)(p - (char*)ptok), stream);

  const int n4w = NEXP * IDIM * HDIM / 4;
  prep_kernel<<<PREP_GRID, 256, 0, stream>>>(x, wg, logits, tki, tkg, counts, xb,
                                             wfc, wfcb, n4w, wpj, wpb, 2 * n4w);
  scatter_kernel<<<NUM_T / 256, 256, 0, stream>>>(tki, tkg, counts, off, fill, ptok, pgate, inv);

  fc_gemm<<<(IDIM / 128) * RB, 256, 0, stream>>>(xb, wfcb, ptok, off, act);
  proj_gemm<<<(HDIM / 128) * RB, 256, 0, stream>>>(act, wpb, pgate, off, pair);
  combine_kernel<<<NUM_T * HDIM / 8 / 256, 256, 0, stream>>>(pair, inv, out);
}